// Round 3
// baseline (625.606 us; speedup 1.0000x reference)
//
#include <hip/hip_runtime.h>
#include <cstdint>
#include <cstddef>

// ---------------------------------------------------------------------------
// BatchTreeEncoder on MFMA: A=4, D=7, B=64, E=128, H=128, N_NODES=5461
// bf16 mfma_f32_16x16x32_bf16, fp32 accumulate. h stored bf16.
// Level-d output max folded into level-(d-1) attention staging (child slab
// already passes through LDS there); level-0 folded in decode_out.
// ---------------------------------------------------------------------------

typedef short  bf16x8 __attribute__((ext_vector_type(8)));
typedef float  f32x4  __attribute__((ext_vector_type(4)));

// workspace layout (bytes)
#define WS_ACC   0u                      // 32*8192*4 = 1 MB
#define WS_WIH   1048576u                // 384*128*2 = 96 KB
#define WS_WHH   (WS_WIH + 98304u)
#define WS_SWT   (WS_WHH + 98304u)       // 128*128*2 = 32 KB
#define WS_EMB   2097152u                // 50000*128*2 = 12.8 MB
#define WS_HA    (WS_EMB + 13107200u)    // 4096*64*128*2 = 64 MB (even levels)
#define WS_HB    (WS_HA + 67108864u)     // 16 MB (odd levels)
#define WS_H0    (WS_HB + 16777216u)     // 16 MB (attention out)
// total ~112 MB

__device__ __forceinline__ float sigm(float x)   { return 1.0f / (1.0f + __expf(-x)); }
__device__ __forceinline__ float tanhf_(float x) { return 1.0f - 2.0f / (1.0f + __expf(2.0f * x)); }

__device__ __forceinline__ unsigned short f2b(float f) {
  unsigned u = __float_as_uint(f);
  u += 0x7fffu + ((u >> 16) & 1u);     // RNE (no NaN here)
  return (unsigned short)(u >> 16);
}
__device__ __forceinline__ float b2f(unsigned short s) {
  return __uint_as_float(((unsigned)s) << 16);
}

__device__ __forceinline__ unsigned fenc(float f) {
  unsigned u = __float_as_uint(f);
  return (u & 0x80000000u) ? ~u : (u | 0x80000000u);
}
__device__ __forceinline__ float fdec(unsigned e) {
  unsigned u = (e & 0x80000000u) ? (e & 0x7fffffffu) : ~e;
  return __uint_as_float(u);
}

__device__ __forceinline__ f32x4 mfma16(bf16x8 a, bf16x8 b, f32x4 c) {
  return __builtin_amdgcn_mfma_f32_16x16x32_bf16(a, b, c, 0, 0, 0);
}

__global__ __launch_bounds__(256) void init_acc(unsigned* __restrict__ acc) {
  acc[blockIdx.x * 256 + threadIdx.x] = 0u;            // grid 1024
}

// final: max over 32 acc slices, then fold level-0 hout (bf16, 8192 elems)
__global__ __launch_bounds__(256) void decode_out(const unsigned* __restrict__ acc,
                                                  const unsigned short* __restrict__ h0lvl,
                                                  float* __restrict__ out) {
  int i = blockIdx.x * 256 + threadIdx.x;              // grid 32
  unsigned m = 0u;
  for (int s = 0; s < 32; ++s) m = max(m, acc[s * 8192 + i]);
  out[i] = fmaxf(fdec(m), b2f(h0lvl[i]));
}

// fp32 -> bf16 emb table (vectorized: one float4 -> ushort4 per thread)
__global__ __launch_bounds__(256) void prep_emb(const float* __restrict__ emb,
                                                unsigned short* __restrict__ embb) {
  int i = blockIdx.x * 256 + threadIdx.x;              // grid 6250 = 1.6M float4s
  float4 v = *(const float4*)(emb + (size_t)i * 4);
  ushort4 o; o.x = f2b(v.x); o.y = f2b(v.y); o.z = f2b(v.z); o.w = f2b(v.w);
  *(ushort4*)(embb + (size_t)i * 4) = o;
}

// fp32 -> bf16 weights + sent_w transpose (swt[k][h] = sent_w[h][k])
__global__ __launch_bounds__(256) void prep_w(const float* __restrict__ wih,
                                              const float* __restrict__ whh,
                                              const float* __restrict__ sw,
                                              unsigned short* __restrict__ wihb,
                                              unsigned short* __restrict__ whhb,
                                              unsigned short* __restrict__ swtb) {
  int i = blockIdx.x * 256 + threadIdx.x;              // grid 448 = 114688
  if (i < 49152)       wihb[i] = f2b(wih[i]);
  else if (i < 98304)  whhb[i - 49152] = f2b(whh[i - 49152]);
  else { int j = i - 98304; int k = j >> 7, h = j & 127; swtb[j] = f2b(sw[h * 128 + k]); }
}

// ---------------------------------------------------------------------------
// GRU: grid n, block 512 (8 waves). Wave w owns 16 outputs j = w*16+l.
// Gate triplet cols {j, 128+j, 256+j}; r,z over concat-K=256 [x || h0];
// n-gate split accumulators (Cn from x, Ch from h0). B-frags in registers.
// A in LDS, XOR-swizzled 16B chunks (conflict-free b128). No atomics here.
// ---------------------------------------------------------------------------
template <bool HAS_H>
__global__ __launch_bounds__(512, 2) void gru_mfma(
    const int*            __restrict__ tok,
    const unsigned short* __restrict__ embb,   // bf16 table
    const unsigned short* __restrict__ wih,
    const unsigned short* __restrict__ whh,
    const float*          __restrict__ b_ih,
    const float*          __restrict__ b_hh,
    const unsigned short* __restrict__ h0,
    unsigned short*       __restrict__ hout)
{
  constexpr int RS  = HAS_H ? 256 : 128;   // ushorts per LDS row
  constexpr int NKS = HAS_H ? 8 : 4;
  __shared__ unsigned short lds[64 * RS];

  const int node = blockIdx.x;
  const int t = threadIdx.x;

  // stage x: bf16 gather, pure uint4 copies (64 rows x 16 chunks)
  {
    const int* tp = tok + node * 64;
#pragma unroll
    for (int i = 0; i < 2; ++i) {
      int g = t + 512 * i;            // 0..1023
      int m = g >> 4, c = g & 15;
      uint4 v = *(const uint4*)(embb + (size_t)tp[m] * 128 + c * 8);
      *(uint4*)(lds + m * RS + ((c ^ (m & 15)) << 3)) = v;
    }
  }
  if constexpr (HAS_H) {              // stage h0 chunks 16..31
    const unsigned short* hp = h0 + (size_t)node * 8192;
#pragma unroll
    for (int i = 0; i < 2; ++i) {
      int g = t + 512 * i;            // 0..1023
      int m = g >> 4, c16 = g & 15;
      uint4 v = *(const uint4*)(hp + m * 128 + c16 * 8);
      *(uint4*)(lds + m * 256 + ((16 | ((c16 ^ (m & 15)) & 15)) << 3)) = v;
    }
  }

  const int w = __builtin_amdgcn_readfirstlane(t >> 6);
  const int lane = t & 63, l = lane & 15, q = lane >> 4;
  const int j = w * 16 + l;

  // B fragments in registers (rows of W are GEMM cols; frag = 8 contig k)
  bf16x8 Br[NKS], Bz[NKS], Bn[4], Bh[HAS_H ? 4 : 1];
#pragma unroll
  for (int ks = 0; ks < 4; ++ks) {
    const int ko = ks * 32 + q * 8;
    Br[ks] = *(const bf16x8*)(wih + (size_t)j * 128 + ko);
    Bz[ks] = *(const bf16x8*)(wih + (size_t)(128 + j) * 128 + ko);
    Bn[ks] = *(const bf16x8*)(wih + (size_t)(256 + j) * 128 + ko);
    if constexpr (HAS_H) {
      Br[4 + ks] = *(const bf16x8*)(whh + (size_t)j * 128 + ko);
      Bz[4 + ks] = *(const bf16x8*)(whh + (size_t)(128 + j) * 128 + ko);
      Bh[ks]     = *(const bf16x8*)(whh + (size_t)(256 + j) * 128 + ko);
    }
  }

  f32x4 Cr[4] = {{0,0,0,0},{0,0,0,0},{0,0,0,0},{0,0,0,0}};
  f32x4 Cz[4] = {{0,0,0,0},{0,0,0,0},{0,0,0,0},{0,0,0,0}};
  f32x4 Cn[4] = {{0,0,0,0},{0,0,0,0},{0,0,0,0},{0,0,0,0}};
  f32x4 Ch[4] = {{0,0,0,0},{0,0,0,0},{0,0,0,0},{0,0,0,0}};
  __syncthreads();

#pragma unroll
  for (int ks = 0; ks < NKS; ++ks) {
    bf16x8 A[4];
#pragma unroll
    for (int mt = 0; mt < 4; ++mt) {
      int m = mt * 16 + l;
      int c = ks * 4 + q;
      A[mt] = *(const bf16x8*)(lds + m * RS + (((c & 16) | ((c ^ l) & 15)) << 3));
    }
#pragma unroll
    for (int mt = 0; mt < 4; ++mt) {
      Cr[mt] = mfma16(A[mt], Br[ks], Cr[mt]);
      Cz[mt] = mfma16(A[mt], Bz[ks], Cz[mt]);
      if (!HAS_H || ks < 4) Cn[mt] = mfma16(A[mt], Bn[ks & 3], Cn[mt]);
      else                  Ch[mt] = mfma16(A[mt], Bh[ks - 4], Ch[mt]);
    }
  }

  // epilogue: gates in-register (triplet shares lane), bf16 store
  const float bR = b_ih[j] + b_hh[j];
  const float bZ = b_ih[128 + j] + b_hh[128 + j];
  const float bN = b_ih[256 + j];
  const float bH = b_hh[256 + j];

#pragma unroll
  for (int mt = 0; mt < 4; ++mt) {
#pragma unroll
    for (int e = 0; e < 4; ++e) {
      const int b = mt * 16 + q * 4 + e;        // C/D: col=lane&15, row=quad*4+reg
      float r  = sigm(Cr[mt][e] + bR);
      float z  = sigm(Cz[mt][e] + bZ);
      float hn_ = bH + (HAS_H ? Ch[mt][e] : 0.0f);
      float nv = tanhf_(Cn[mt][e] + bN + r * hn_);
      float hp = 0.0f;
      if constexpr (HAS_H) {
        int c16 = j >> 3;
        hp = b2f(lds[b * 256 + ((16 | ((c16 ^ (b & 15)) & 15)) << 3) + (j & 7)]);
      }
      float hv = (1.0f - z) * nv + z * hp;
      hout[(size_t)(node * 64 + b) * 128 + j] = f2b(hv);
    }
  }
}

// ---------------------------------------------------------------------------
// Attention: grid n (parents), block 512 (8 waves: wm=row-half, wn=col-chunk32).
// Folds child-level output max into acc during staging (max over a in-reg,
// one atomic per (b,j) per parent -> 4x fewer atomics than per-child).
// u = ch(256x128) . sent_w via MFMA; s = tanh(sum_k tanh(u+sb)*ctx);
// softmax over a; h0 = sum_a alpha_a * ch_a.
// ---------------------------------------------------------------------------
__global__ __launch_bounds__(512, 2) void attn_mfma(
    const unsigned short* __restrict__ hch,   // child h, rows p*256..
    const unsigned short* __restrict__ swt,   // 128x128 bf16 [k_u][h]
    const float*          __restrict__ sb,
    const float*          __restrict__ ctx,
    unsigned short*       __restrict__ h0out,
    unsigned*             __restrict__ acc)
{
  __shared__ unsigned short chs[256 * 128];   // 64 KB, swizzled
  __shared__ float spart[4][256];
  __shared__ float alf[256];

  const int p = blockIdx.x;
  const int t = threadIdx.x;

  // stage child slab; fold max over the 4 children (a) per (b, j)
  float pm[2][8];
#pragma unroll
  for (int k = 0; k < 8; ++k) { pm[0][k] = -3.4e38f; pm[1][k] = -3.4e38f; }
  const unsigned short* src = hch + (size_t)p * 256 * 128;
#pragma unroll
  for (int i = 0; i < 8; ++i) {
    int g = t + 512 * i;                      // 0..4095 16B-chunks
    int m = g >> 4, c = g & 15;               // m = m0 + 32*i (m0=t>>4, c=t&15)
    uint4 v = *(const uint4*)(src + m * 128 + c * 8);
    *(uint4*)(chs + m * 128 + ((c ^ (m & 15)) << 3)) = v;
    const unsigned short* e = (const unsigned short*)&v;
    float* pmr = pm[i & 1];
#pragma unroll
    for (int k = 0; k < 8; ++k) pmr[k] = fmaxf(pmr[k], b2f(e[k]));
  }
  {
    unsigned* accs = acc + (p & 31) * 8192;
    int b0 = t >> 4, c = t & 15;
#pragma unroll
    for (int k = 0; k < 8; ++k) {
      atomicMax(accs + b0 * 128 + c * 8 + k, fenc(pm[0][k]));
      atomicMax(accs + (b0 + 32) * 128 + c * 8 + k, fenc(pm[1][k]));
    }
  }

  const int w = __builtin_amdgcn_readfirstlane(t >> 6);
  const int wm = w >> 2, wn = w & 3;
  const int lane = t & 63, l = lane & 15, q = lane >> 4;

  bf16x8 Bs[2][4];
#pragma unroll
  for (int nt = 0; nt < 2; ++nt)
#pragma unroll
    for (int ks = 0; ks < 4; ++ks)
      Bs[nt][ks] = *(const bf16x8*)(swt + (size_t)(wn * 32 + nt * 16 + l) * 128 + ks * 32 + q * 8);

  f32x4 Cu[8][2] = {};
  __syncthreads();

#pragma unroll
  for (int ks = 0; ks < 4; ++ks) {
#pragma unroll
    for (int mt = 0; mt < 8; ++mt) {
      int m = wm * 128 + mt * 16 + l;
      int c = ks * 4 + q;
      bf16x8 A = *(const bf16x8*)(chs + m * 128 + (((c ^ (m & 15)) & 15) << 3));
      Cu[mt][0] = mfma16(A, Bs[0][ks], Cu[mt][0]);
      Cu[mt][1] = mfma16(A, Bs[1][ks], Cu[mt][1]);
    }
  }

  const float sb0 = sb[wn * 32 + l],  sb1 = sb[wn * 32 + 16 + l];
  const float cx0 = ctx[wn * 32 + l], cx1 = ctx[wn * 32 + 16 + l];
#pragma unroll
  for (int mt = 0; mt < 8; ++mt) {
    float pe[4];
#pragma unroll
    for (int e = 0; e < 4; ++e)
      pe[e] = tanhf_(Cu[mt][0][e] + sb0) * cx0 + tanhf_(Cu[mt][1][e] + sb1) * cx1;
#pragma unroll
    for (int mask = 1; mask < 16; mask <<= 1)
#pragma unroll
      for (int e = 0; e < 4; ++e)
        pe[e] += __shfl_xor(pe[e], mask, 16);
    if (l == 0) {
      int r = wm * 128 + mt * 16 + q * 4;
#pragma unroll
      for (int e = 0; e < 4; ++e) spart[wn][r + e] = pe[e];
    }
  }
  __syncthreads();

  if (t < 256) {
    float s = tanhf_(spart[0][t] + spart[1][t] + spart[2][t] + spart[3][t]);
    spart[0][t] = s;                          // reuse row 0 as s-values
  }
  __syncthreads();
  if (t < 64) {
    float s0 = spart[0][t], s1 = spart[0][64 + t], s2 = spart[0][128 + t], s3 = spart[0][192 + t];
    float m = fmaxf(fmaxf(s0, s1), fmaxf(s2, s3));
    float e0 = __expf(s0 - m), e1 = __expf(s1 - m), e2 = __expf(s2 - m), e3 = __expf(s3 - m);
    float inv = 1.0f / (e0 + e1 + e2 + e3);
    alf[t] = e0 * inv; alf[64 + t] = e1 * inv; alf[128 + t] = e2 * inv; alf[192 + t] = e3 * inv;
  }
  __syncthreads();

#pragma unroll
  for (int i = 0; i < 2; ++i) {
    int id = t + 512 * i;                     // 0..1023: (b, chunk)
    int b = id >> 4, c = id & 15;
    float o[8] = {0,0,0,0,0,0,0,0};
#pragma unroll
    for (int a = 0; a < 4; ++a) {
      int m = a * 64 + b;
      const unsigned short* rp = chs + m * 128 + ((c ^ (m & 15)) << 3);
      float al = alf[a * 64 + b];
#pragma unroll
      for (int k = 0; k < 8; ++k) o[k] += al * b2f(rp[k]);
    }
    ushort4 o0, o1;
    o0.x = f2b(o[0]); o0.y = f2b(o[1]); o0.z = f2b(o[2]); o0.w = f2b(o[3]);
    o1.x = f2b(o[4]); o1.y = f2b(o[5]); o1.z = f2b(o[6]); o1.w = f2b(o[7]);
    *(ushort4*)(h0out + (size_t)(p * 64 + b) * 128 + c * 8)     = o0;
    *(ushort4*)(h0out + (size_t)(p * 64 + b) * 128 + c * 8 + 4) = o1;
  }
}

extern "C" void kernel_launch(void* const* d_in, const int* in_sizes, int n_in,
                              void* d_out, int out_size, void* d_ws, size_t ws_size,
                              hipStream_t stream) {
  const int*   tokens = (const int*)d_in[0];
  const float* emb    = (const float*)d_in[1];
  const float* sent_w = (const float*)d_in[2];
  const float* sent_b = (const float*)d_in[3];
  const float* ctx_w  = (const float*)d_in[4];
  const float* w_ih   = (const float*)d_in[5];
  const float* w_hh   = (const float*)d_in[6];
  const float* b_ih   = (const float*)d_in[7];
  const float* b_hh   = (const float*)d_in[8];

  char* ws = (char*)d_ws;
  unsigned*       acc  = (unsigned*)(ws + WS_ACC);
  unsigned short* wihb = (unsigned short*)(ws + WS_WIH);
  unsigned short* whhb = (unsigned short*)(ws + WS_WHH);
  unsigned short* swtb = (unsigned short*)(ws + WS_SWT);
  unsigned short* embb = (unsigned short*)(ws + WS_EMB);
  unsigned short* hA   = (unsigned short*)(ws + WS_HA);
  unsigned short* hB   = (unsigned short*)(ws + WS_HB);
  unsigned short* h0b  = (unsigned short*)(ws + WS_H0);

  hipLaunchKernelGGL(init_acc, dim3(1024), dim3(256), 0, stream, acc);
  hipLaunchKernelGGL(prep_emb, dim3(6250), dim3(256), 0, stream, emb, embb);
  hipLaunchKernelGGL(prep_w, dim3(448), dim3(256), 0, stream,
                     w_ih, w_hh, sent_w, wihb, whhb, swtb);

  static const int offs[7] = {0, 1, 5, 21, 85, 341, 1365};
  for (int d = 6; d >= 0; --d) {
    int n = 1 << (2 * d);
    int off = offs[d];
    unsigned short* hout = (d & 1) ? hB : hA;
    if (d < 6) {
      unsigned short* child = (d & 1) ? hA : hB;   // level d+1 output
      hipLaunchKernelGGL(attn_mfma, dim3(n), dim3(512), 0, stream,
                         child, swtb, sent_b, ctx_w, h0b, acc);
      hipLaunchKernelGGL((gru_mfma<true>), dim3(n), dim3(512), 0, stream,
                         tokens + (size_t)off * 64, embb, wihb, whhb, b_ih, b_hh,
                         h0b, hout);
    } else {
      hipLaunchKernelGGL((gru_mfma<false>), dim3(n), dim3(512), 0, stream,
                         tokens + (size_t)off * 64, embb, wihb, whhb, b_ih, b_hh,
                         (const unsigned short*)nullptr, hout);
    }
  }
  hipLaunchKernelGGL(decode_out, dim3(32), dim3(256), 0, stream, acc, hA, (float*)d_out);
}

// Round 4
// 441.803 us; speedup vs baseline: 1.4160x; 1.4160x over previous
//
#include <hip/hip_runtime.h>
#include <cstdint>
#include <cstddef>

// ---------------------------------------------------------------------------
// BatchTreeEncoder on MFMA: A=4, D=7, B=64, E=128, H=128, N_NODES=5461
// bf16 mfma_f32_16x16x32_bf16, fp32 accumulate. h stored bf16.
// Cross-node max: per-level reduce kernel, slice-per-block plain RMW into a
// 32-slice acc (NO atomics — R3 showed atomics write through the XCD L2s at
// ~31B/atomic when the wave pattern spans many lines: 278MB -> 220us).
// ---------------------------------------------------------------------------

typedef short  bf16x8 __attribute__((ext_vector_type(8)));
typedef float  f32x4  __attribute__((ext_vector_type(4)));

// workspace layout (bytes)
#define WS_ACC   0u                      // 32*8192*4 = 1 MB
#define WS_WIH   1048576u                // 384*128*2 = 96 KB
#define WS_WHH   (WS_WIH + 98304u)
#define WS_SWT   (WS_WHH + 98304u)       // 128*128*2 = 32 KB
#define WS_EMB   2097152u                // 50000*128*2 = 12.8 MB
#define WS_HA    (WS_EMB + 13107200u)    // 4096*64*128*2 = 64 MB (even levels)
#define WS_HB    (WS_HA + 67108864u)     // 16 MB (odd levels)
#define WS_H0    (WS_HB + 16777216u)     // 16 MB (attention out)
// total ~112 MB

__device__ __forceinline__ float sigm(float x)   { return 1.0f / (1.0f + __expf(-x)); }
__device__ __forceinline__ float tanhf_(float x) { return 1.0f - 2.0f / (1.0f + __expf(2.0f * x)); }

__device__ __forceinline__ unsigned short f2b(float f) {
  unsigned u = __float_as_uint(f);
  u += 0x7fffu + ((u >> 16) & 1u);     // RNE (no NaN here)
  return (unsigned short)(u >> 16);
}
__device__ __forceinline__ float b2f(unsigned short s) {
  return __uint_as_float(((unsigned)s) << 16);
}

__device__ __forceinline__ unsigned fenc(float f) {
  unsigned u = __float_as_uint(f);
  return (u & 0x80000000u) ? ~u : (u | 0x80000000u);
}
__device__ __forceinline__ float fdec(unsigned e) {
  unsigned u = (e & 0x80000000u) ? (e & 0x7fffffffu) : ~e;
  return __uint_as_float(u);
}

__device__ __forceinline__ f32x4 mfma16(bf16x8 a, bf16x8 b, f32x4 c) {
  return __builtin_amdgcn_mfma_f32_16x16x32_bf16(a, b, c, 0, 0, 0);
}

__global__ __launch_bounds__(256) void init_acc(unsigned* __restrict__ acc) {
  acc[blockIdx.x * 256 + threadIdx.x] = 0u;            // grid 1024
}

__global__ __launch_bounds__(256) void decode_out(const unsigned* __restrict__ acc,
                                                  float* __restrict__ out) {
  int i = blockIdx.x * 256 + threadIdx.x;              // grid 32
  unsigned m = 0u;
  for (int s = 0; s < 32; ++s) m = max(m, acc[s * 8192 + i]);
  out[i] = fdec(m);
}

// per-level max over nodes. grid (8, nch), block 256: thread owns 4 elems,
// loops ch nodes, then plain load-max-store to its exclusive (slice, elem).
__global__ __launch_bounds__(256) void reduce_lvl(const unsigned short* __restrict__ h,
                                                  int n, int ch,
                                                  unsigned* __restrict__ acc) {
  int i4 = blockIdx.x * 256 + threadIdx.x;             // 0..2047 (elem group of 4)
  int n0 = blockIdx.y * ch;
  int n1 = n0 + ch; if (n1 > n) n1 = n;
  float m0 = -3.4e38f, m1 = m0, m2 = m0, m3 = m0;
  for (int node = n0; node < n1; ++node) {
    uint2 v = *(const uint2*)(h + (size_t)node * 8192 + i4 * 4);
    m0 = fmaxf(m0, b2f((unsigned short)(v.x & 0xffffu)));
    m1 = fmaxf(m1, b2f((unsigned short)(v.x >> 16)));
    m2 = fmaxf(m2, b2f((unsigned short)(v.y & 0xffffu)));
    m3 = fmaxf(m3, b2f((unsigned short)(v.y >> 16)));
  }
  unsigned* a = acc + (size_t)blockIdx.y * 8192 + i4 * 4;  // blockIdx.y < 32 always
  a[0] = max(a[0], fenc(m0));
  a[1] = max(a[1], fenc(m1));
  a[2] = max(a[2], fenc(m2));
  a[3] = max(a[3], fenc(m3));
}

// fp32 -> bf16 emb table (vectorized: one float4 -> ushort4 per thread)
__global__ __launch_bounds__(256) void prep_emb(const float* __restrict__ emb,
                                                unsigned short* __restrict__ embb) {
  int i = blockIdx.x * 256 + threadIdx.x;              // grid 6250 = 1.6M float4s
  float4 v = *(const float4*)(emb + (size_t)i * 4);
  ushort4 o; o.x = f2b(v.x); o.y = f2b(v.y); o.z = f2b(v.z); o.w = f2b(v.w);
  *(ushort4*)(embb + (size_t)i * 4) = o;
}

// fp32 -> bf16 weights + sent_w transpose (swt[k][h] = sent_w[h][k])
__global__ __launch_bounds__(256) void prep_w(const float* __restrict__ wih,
                                              const float* __restrict__ whh,
                                              const float* __restrict__ sw,
                                              unsigned short* __restrict__ wihb,
                                              unsigned short* __restrict__ whhb,
                                              unsigned short* __restrict__ swtb) {
  int i = blockIdx.x * 256 + threadIdx.x;              // grid 448 = 114688
  if (i < 49152)       wihb[i] = f2b(wih[i]);
  else if (i < 98304)  whhb[i - 49152] = f2b(whh[i - 49152]);
  else { int j = i - 98304; int k = j >> 7, h = j & 127; swtb[j] = f2b(sw[h * 128 + k]); }
}

// ---------------------------------------------------------------------------
// GRU: grid n, block 512 (8 waves). Wave w owns 16 outputs j = w*16+l.
// Gate triplet cols {j, 128+j, 256+j}; r,z over concat-K=256 [x || h0];
// n-gate split accumulators (Cn from x, Ch from h0). B-frags in registers.
// A in LDS, XOR-swizzled 16B chunks (conflict-free b128). No atomics.
// ---------------------------------------------------------------------------
template <bool HAS_H>
__global__ __launch_bounds__(512, 2) void gru_mfma(
    const int*            __restrict__ tok,
    const unsigned short* __restrict__ embb,   // bf16 table
    const unsigned short* __restrict__ wih,
    const unsigned short* __restrict__ whh,
    const float*          __restrict__ b_ih,
    const float*          __restrict__ b_hh,
    const unsigned short* __restrict__ h0,
    unsigned short*       __restrict__ hout)
{
  constexpr int RS  = HAS_H ? 256 : 128;   // ushorts per LDS row
  constexpr int NKS = HAS_H ? 8 : 4;
  __shared__ unsigned short lds[64 * RS];

  const int node = blockIdx.x;
  const int t = threadIdx.x;

  // stage x: bf16 gather, pure uint4 copies (64 rows x 16 chunks)
  {
    const int* tp = tok + node * 64;
#pragma unroll
    for (int i = 0; i < 2; ++i) {
      int g = t + 512 * i;            // 0..1023
      int m = g >> 4, c = g & 15;
      uint4 v = *(const uint4*)(embb + (size_t)tp[m] * 128 + c * 8);
      *(uint4*)(lds + m * RS + ((c ^ (m & 15)) << 3)) = v;
    }
  }
  if constexpr (HAS_H) {              // stage h0 chunks 16..31
    const unsigned short* hp = h0 + (size_t)node * 8192;
#pragma unroll
    for (int i = 0; i < 2; ++i) {
      int g = t + 512 * i;            // 0..1023
      int m = g >> 4, c16 = g & 15;
      uint4 v = *(const uint4*)(hp + m * 128 + c16 * 8);
      *(uint4*)(lds + m * 256 + ((16 | ((c16 ^ (m & 15)) & 15)) << 3)) = v;
    }
  }

  const int w = __builtin_amdgcn_readfirstlane(t >> 6);
  const int lane = t & 63, l = lane & 15, q = lane >> 4;
  const int j = w * 16 + l;

  // B fragments in registers (rows of W are GEMM cols; frag = 8 contig k)
  bf16x8 Br[NKS], Bz[NKS], Bn[4], Bh[HAS_H ? 4 : 1];
#pragma unroll
  for (int ks = 0; ks < 4; ++ks) {
    const int ko = ks * 32 + q * 8;
    Br[ks] = *(const bf16x8*)(wih + (size_t)j * 128 + ko);
    Bz[ks] = *(const bf16x8*)(wih + (size_t)(128 + j) * 128 + ko);
    Bn[ks] = *(const bf16x8*)(wih + (size_t)(256 + j) * 128 + ko);
    if constexpr (HAS_H) {
      Br[4 + ks] = *(const bf16x8*)(whh + (size_t)j * 128 + ko);
      Bz[4 + ks] = *(const bf16x8*)(whh + (size_t)(128 + j) * 128 + ko);
      Bh[ks]     = *(const bf16x8*)(whh + (size_t)(256 + j) * 128 + ko);
    }
  }

  f32x4 Cr[4] = {{0,0,0,0},{0,0,0,0},{0,0,0,0},{0,0,0,0}};
  f32x4 Cz[4] = {{0,0,0,0},{0,0,0,0},{0,0,0,0},{0,0,0,0}};
  f32x4 Cn[4] = {{0,0,0,0},{0,0,0,0},{0,0,0,0},{0,0,0,0}};
  f32x4 Ch[4] = {{0,0,0,0},{0,0,0,0},{0,0,0,0},{0,0,0,0}};
  __syncthreads();

#pragma unroll
  for (int ks = 0; ks < NKS; ++ks) {
    bf16x8 A[4];
#pragma unroll
    for (int mt = 0; mt < 4; ++mt) {
      int m = mt * 16 + l;
      int c = ks * 4 + q;
      A[mt] = *(const bf16x8*)(lds + m * RS + (((c & 16) | ((c ^ l) & 15)) << 3));
    }
#pragma unroll
    for (int mt = 0; mt < 4; ++mt) {
      Cr[mt] = mfma16(A[mt], Br[ks], Cr[mt]);
      Cz[mt] = mfma16(A[mt], Bz[ks], Cz[mt]);
      if (!HAS_H || ks < 4) Cn[mt] = mfma16(A[mt], Bn[ks & 3], Cn[mt]);
      else                  Ch[mt] = mfma16(A[mt], Bh[ks - 4], Ch[mt]);
    }
  }

  // epilogue: gates in-register (triplet shares lane), bf16 store
  const float bR = b_ih[j] + b_hh[j];
  const float bZ = b_ih[128 + j] + b_hh[128 + j];
  const float bN = b_ih[256 + j];
  const float bH = b_hh[256 + j];

#pragma unroll
  for (int mt = 0; mt < 4; ++mt) {
#pragma unroll
    for (int e = 0; e < 4; ++e) {
      const int b = mt * 16 + q * 4 + e;        // C/D: col=lane&15, row=quad*4+reg
      float r  = sigm(Cr[mt][e] + bR);
      float z  = sigm(Cz[mt][e] + bZ);
      float hn_ = bH + (HAS_H ? Ch[mt][e] : 0.0f);
      float nv = tanhf_(Cn[mt][e] + bN + r * hn_);
      float hp = 0.0f;
      if constexpr (HAS_H) {
        int c16 = j >> 3;
        hp = b2f(lds[b * 256 + ((16 | ((c16 ^ (b & 15)) & 15)) << 3) + (j & 7)]);
      }
      float hv = (1.0f - z) * nv + z * hp;
      hout[(size_t)(node * 64 + b) * 128 + j] = f2b(hv);
    }
  }
}

// ---------------------------------------------------------------------------
// Attention: grid n (parents), block 512 (8 waves: wm=row-half, wn=col-chunk32).
// u = ch(256x128) . sent_w via MFMA; s = tanh(sum_k tanh(u+sb)*ctx);
// softmax over a; h0 = sum_a alpha_a * ch_a. No atomics (R3 lesson).
// ---------------------------------------------------------------------------
__global__ __launch_bounds__(512, 2) void attn_mfma(
    const unsigned short* __restrict__ hch,   // child h, rows p*256..
    const unsigned short* __restrict__ swt,   // 128x128 bf16 [k_u][h]
    const float*          __restrict__ sb,
    const float*          __restrict__ ctx,
    unsigned short*       __restrict__ h0out)
{
  __shared__ unsigned short chs[256 * 128];   // 64 KB, swizzled
  __shared__ float spart[4][256];
  __shared__ float alf[256];

  const int p = blockIdx.x;
  const int t = threadIdx.x;

  const unsigned short* src = hch + (size_t)p * 256 * 128;
#pragma unroll
  for (int i = 0; i < 8; ++i) {
    int g = t + 512 * i;                      // 0..4095 16B-chunks
    int m = g >> 4, c = g & 15;
    uint4 v = *(const uint4*)(src + m * 128 + c * 8);
    *(uint4*)(chs + m * 128 + ((c ^ (m & 15)) << 3)) = v;
  }

  const int w = __builtin_amdgcn_readfirstlane(t >> 6);
  const int wm = w >> 2, wn = w & 3;
  const int lane = t & 63, l = lane & 15, q = lane >> 4;

  bf16x8 Bs[2][4];
#pragma unroll
  for (int nt = 0; nt < 2; ++nt)
#pragma unroll
    for (int ks = 0; ks < 4; ++ks)
      Bs[nt][ks] = *(const bf16x8*)(swt + (size_t)(wn * 32 + nt * 16 + l) * 128 + ks * 32 + q * 8);

  f32x4 Cu[8][2] = {};
  __syncthreads();

#pragma unroll
  for (int ks = 0; ks < 4; ++ks) {
#pragma unroll
    for (int mt = 0; mt < 8; ++mt) {
      int m = wm * 128 + mt * 16 + l;
      int c = ks * 4 + q;
      bf16x8 A = *(const bf16x8*)(chs + m * 128 + (((c ^ (m & 15)) & 15) << 3));
      Cu[mt][0] = mfma16(A, Bs[0][ks], Cu[mt][0]);
      Cu[mt][1] = mfma16(A, Bs[1][ks], Cu[mt][1]);
    }
  }

  const float sb0 = sb[wn * 32 + l],  sb1 = sb[wn * 32 + 16 + l];
  const float cx0 = ctx[wn * 32 + l], cx1 = ctx[wn * 32 + 16 + l];
#pragma unroll
  for (int mt = 0; mt < 8; ++mt) {
    float pe[4];
#pragma unroll
    for (int e = 0; e < 4; ++e)
      pe[e] = tanhf_(Cu[mt][0][e] + sb0) * cx0 + tanhf_(Cu[mt][1][e] + sb1) * cx1;
#pragma unroll
    for (int mask = 1; mask < 16; mask <<= 1)
#pragma unroll
      for (int e = 0; e < 4; ++e)
        pe[e] += __shfl_xor(pe[e], mask, 16);
    if (l == 0) {
      int r = wm * 128 + mt * 16 + q * 4;
#pragma unroll
      for (int e = 0; e < 4; ++e) spart[wn][r + e] = pe[e];
    }
  }
  __syncthreads();

  if (t < 256) {
    float s = tanhf_(spart[0][t] + spart[1][t] + spart[2][t] + spart[3][t]);
    spart[0][t] = s;                          // reuse row 0 as s-values
  }
  __syncthreads();
  if (t < 64) {
    float s0 = spart[0][t], s1 = spart[0][64 + t], s2 = spart[0][128 + t], s3 = spart[0][192 + t];
    float m = fmaxf(fmaxf(s0, s1), fmaxf(s2, s3));
    float e0 = __expf(s0 - m), e1 = __expf(s1 - m), e2 = __expf(s2 - m), e3 = __expf(s3 - m);
    float inv = 1.0f / (e0 + e1 + e2 + e3);
    alf[t] = e0 * inv; alf[64 + t] = e1 * inv; alf[128 + t] = e2 * inv; alf[192 + t] = e3 * inv;
  }
  __syncthreads();

#pragma unroll
  for (int i = 0; i < 2; ++i) {
    int id = t + 512 * i;                     // 0..1023: (b, chunk)
    int b = id >> 4, c = id & 15;
    float o[8] = {0,0,0,0,0,0,0,0};
#pragma unroll
    for (int a = 0; a < 4; ++a) {
      int m = a * 64 + b;
      const unsigned short* rp = chs + m * 128 + ((c ^ (m & 15)) << 3);
      float al = alf[a * 64 + b];
#pragma unroll
      for (int k = 0; k < 8; ++k) o[k] += al * b2f(rp[k]);
    }
    ushort4 o0, o1;
    o0.x = f2b(o[0]); o0.y = f2b(o[1]); o0.z = f2b(o[2]); o0.w = f2b(o[3]);
    o1.x = f2b(o[4]); o1.y = f2b(o[5]); o1.z = f2b(o[6]); o1.w = f2b(o[7]);
    *(ushort4*)(h0out + (size_t)(p * 64 + b) * 128 + c * 8)     = o0;
    *(ushort4*)(h0out + (size_t)(p * 64 + b) * 128 + c * 8 + 4) = o1;
  }
}

extern "C" void kernel_launch(void* const* d_in, const int* in_sizes, int n_in,
                              void* d_out, int out_size, void* d_ws, size_t ws_size,
                              hipStream_t stream) {
  const int*   tokens = (const int*)d_in[0];
  const float* emb    = (const float*)d_in[1];
  const float* sent_w = (const float*)d_in[2];
  const float* sent_b = (const float*)d_in[3];
  const float* ctx_w  = (const float*)d_in[4];
  const float* w_ih   = (const float*)d_in[5];
  const float* w_hh   = (const float*)d_in[6];
  const float* b_ih   = (const float*)d_in[7];
  const float* b_hh   = (const float*)d_in[8];

  char* ws = (char*)d_ws;
  unsigned*       acc  = (unsigned*)(ws + WS_ACC);
  unsigned short* wihb = (unsigned short*)(ws + WS_WIH);
  unsigned short* whhb = (unsigned short*)(ws + WS_WHH);
  unsigned short* swtb = (unsigned short*)(ws + WS_SWT);
  unsigned short* embb = (unsigned short*)(ws + WS_EMB);
  unsigned short* hA   = (unsigned short*)(ws + WS_HA);
  unsigned short* hB   = (unsigned short*)(ws + WS_HB);
  unsigned short* h0b  = (unsigned short*)(ws + WS_H0);

  hipLaunchKernelGGL(init_acc, dim3(1024), dim3(256), 0, stream, acc);
  hipLaunchKernelGGL(prep_emb, dim3(6250), dim3(256), 0, stream, emb, embb);
  hipLaunchKernelGGL(prep_w, dim3(448), dim3(256), 0, stream,
                     w_ih, w_hh, sent_w, wihb, whhb, swtb);

  static const int offs[7] = {0, 1, 5, 21, 85, 341, 1365};
  for (int d = 6; d >= 0; --d) {
    int n = 1 << (2 * d);
    int off = offs[d];
    unsigned short* hout = (d & 1) ? hB : hA;
    if (d < 6) {
      unsigned short* child = (d & 1) ? hA : hB;   // level d+1 output
      hipLaunchKernelGGL(attn_mfma, dim3(n), dim3(512), 0, stream,
                         child, swtb, sent_b, ctx_w, h0b);
      hipLaunchKernelGGL((gru_mfma<true>), dim3(n), dim3(512), 0, stream,
                         tokens + (size_t)off * 64, embb, wihb, whhb, b_ih, b_hh,
                         h0b, hout);
    } else {
      hipLaunchKernelGGL((gru_mfma<false>), dim3(n), dim3(512), 0, stream,
                         tokens + (size_t)off * 64, embb, wihb, whhb, b_ih, b_hh,
                         (const unsigned short*)nullptr, hout);
    }
    int ch  = (n + 31) / 32;
    int nch = (n + ch - 1) / ch;
    hipLaunchKernelGGL(reduce_lvl, dim3(8, nch), dim3(256), 0, stream, hout, n, ch, acc);
  }
  hipLaunchKernelGGL(decode_out, dim3(32), dim3(256), 0, stream, acc, (float*)d_out);
}

// Round 5
// 401.495 us; speedup vs baseline: 1.5582x; 1.1004x over previous
//
#include <hip/hip_runtime.h>
#include <cstdint>
#include <cstddef>

// ---------------------------------------------------------------------------
// BatchTreeEncoder on MFMA: A=4, D=7, B=64, E=128, H=128, N_NODES=5461
// R5: fused attn+gru per level (h0 stays in LDS); unified H buffer holding all
// 5461 node outputs at tree offsets; single reduce_all + decode (no atomics,
// no init). 10 dispatches total (was 26).
// ---------------------------------------------------------------------------

typedef short  bf16x8 __attribute__((ext_vector_type(8)));
typedef float  f32x4  __attribute__((ext_vector_type(4)));

// workspace layout (bytes)
#define WS_ACC   0u                        // 64*8192*4 = 2 MB (write-only slices)
#define WS_WIH   2097152u                  // 384*128*2
#define WS_WHH   (WS_WIH + 98304u)
#define WS_SWT   (WS_WHH + 98304u)         // 128*128*2
#define WS_EMB   (WS_SWT + 32768u)         // 50000*128*2 = 12.8 MB
#define WS_H     (WS_EMB + 12800000u)      // 5461*8192*2 = 89.5 MB (all levels)
// total ~105 MB

__device__ __forceinline__ float sigm(float x)   { return 1.0f / (1.0f + __expf(-x)); }
// 1 - sigm(x) = 1/(1+exp(x))
__device__ __forceinline__ float sigmc(float x)  { return 1.0f / (1.0f + __expf(x)); }
__device__ __forceinline__ float tanhf_(float x) { return 1.0f - 2.0f / (1.0f + __expf(2.0f * x)); }

__device__ __forceinline__ unsigned short f2b(float f) {
  unsigned u = __float_as_uint(f);
  u += 0x7fffu + ((u >> 16) & 1u);     // RNE (no NaN here)
  return (unsigned short)(u >> 16);
}
__device__ __forceinline__ float b2f(unsigned short s) {
  return __uint_as_float(((unsigned)s) << 16);
}

__device__ __forceinline__ unsigned fenc(float f) {
  unsigned u = __float_as_uint(f);
  return (u & 0x80000000u) ? ~u : (u | 0x80000000u);
}
__device__ __forceinline__ float fdec(unsigned e) {
  unsigned u = (e & 0x80000000u) ? (e & 0x7fffffffu) : ~e;
  return __uint_as_float(u);
}

__device__ __forceinline__ f32x4 mfma16(bf16x8 a, bf16x8 b, f32x4 c) {
  return __builtin_amdgcn_mfma_f32_16x16x32_bf16(a, b, c, 0, 0, 0);
}

// max over all 5461 nodes. grid (8, 64), block 256: thread owns 4 elems,
// loops 86 nodes, stores to its EXCLUSIVE (slice, elem) slot (no init needed).
__global__ __launch_bounds__(256) void reduce_all(const unsigned short* __restrict__ H,
                                                  unsigned* __restrict__ acc) {
  int i4 = blockIdx.x * 256 + threadIdx.x;             // 0..2047 (elem group of 4)
  int n0 = blockIdx.y * 86;
  int n1 = n0 + 86; if (n1 > 5461) n1 = 5461;
  float m0 = -3.4e38f, m1 = m0, m2 = m0, m3 = m0;
  for (int node = n0; node < n1; ++node) {
    uint2 v = *(const uint2*)(H + (size_t)node * 8192 + i4 * 4);
    m0 = fmaxf(m0, b2f((unsigned short)(v.x & 0xffffu)));
    m1 = fmaxf(m1, b2f((unsigned short)(v.x >> 16)));
    m2 = fmaxf(m2, b2f((unsigned short)(v.y & 0xffffu)));
    m3 = fmaxf(m3, b2f((unsigned short)(v.y >> 16)));
  }
  unsigned* a = acc + (size_t)blockIdx.y * 8192 + i4 * 4;
  a[0] = fenc(m0); a[1] = fenc(m1); a[2] = fenc(m2); a[3] = fenc(m3);
}

__global__ __launch_bounds__(256) void decode_out(const unsigned* __restrict__ acc,
                                                  float* __restrict__ out) {
  int i = blockIdx.x * 256 + threadIdx.x;              // grid 32
  unsigned m = 0u;
  for (int s = 0; s < 64; ++s) m = max(m, acc[s * 8192 + i]);
  out[i] = fdec(m);
}

// fp32 -> bf16 emb table
__global__ __launch_bounds__(256) void prep_emb(const float* __restrict__ emb,
                                                unsigned short* __restrict__ embb) {
  int i = blockIdx.x * 256 + threadIdx.x;              // grid 6250 = 1.6M float4s
  float4 v = *(const float4*)(emb + (size_t)i * 4);
  ushort4 o; o.x = f2b(v.x); o.y = f2b(v.y); o.z = f2b(v.z); o.w = f2b(v.w);
  *(ushort4*)(embb + (size_t)i * 4) = o;
}

// fp32 -> bf16 weights + sent_w transpose (swt[k][h] = sent_w[h][k])
__global__ __launch_bounds__(256) void prep_w(const float* __restrict__ wih,
                                              const float* __restrict__ whh,
                                              const float* __restrict__ sw,
                                              unsigned short* __restrict__ wihb,
                                              unsigned short* __restrict__ whhb,
                                              unsigned short* __restrict__ swtb) {
  int i = blockIdx.x * 256 + threadIdx.x;              // grid 448 = 114688
  if (i < 49152)       wihb[i] = f2b(wih[i]);
  else if (i < 98304)  whhb[i - 49152] = f2b(whh[i - 49152]);
  else { int j = i - 98304; int k = j >> 7, h = j & 127; swtb[j] = f2b(sw[h * 128 + k]); }
}

// ---------------------------------------------------------------------------
// Leaf GRU (h0 = 0): grid 4096, block 512 (8 waves). Wave w owns j = w*16+l.
// ---------------------------------------------------------------------------
__global__ __launch_bounds__(512, 2) void gru_leaf(
    const int*            __restrict__ tok,
    const unsigned short* __restrict__ embb,
    const unsigned short* __restrict__ wih,
    const float*          __restrict__ b_ih,
    const float*          __restrict__ b_hh,
    unsigned short*       __restrict__ hout)
{
  __shared__ unsigned short xs[8192];

  const int node = blockIdx.x;
  const int t = threadIdx.x;

  {
    const int* tp = tok + node * 64;
#pragma unroll
    for (int i = 0; i < 2; ++i) {
      int g = t + 512 * i;
      int m = g >> 4, c = g & 15;
      uint4 v = *(const uint4*)(embb + (size_t)tp[m] * 128 + c * 8);
      *(uint4*)(xs + m * 128 + ((c ^ (m & 15)) << 3)) = v;
    }
  }

  const int w = __builtin_amdgcn_readfirstlane(t >> 6);
  const int lane = t & 63, l = lane & 15, q = lane >> 4;
  const int j = w * 16 + l;

  bf16x8 Br[4], Bz[4], Bn[4];
#pragma unroll
  for (int ks = 0; ks < 4; ++ks) {
    const int ko = ks * 32 + q * 8;
    Br[ks] = *(const bf16x8*)(wih + (size_t)j * 128 + ko);
    Bz[ks] = *(const bf16x8*)(wih + (size_t)(128 + j) * 128 + ko);
    Bn[ks] = *(const bf16x8*)(wih + (size_t)(256 + j) * 128 + ko);
  }

  f32x4 Cr[4] = {}, Cz[4] = {}, Cn[4] = {};
  __syncthreads();

#pragma unroll
  for (int ks = 0; ks < 4; ++ks) {
    bf16x8 A[4];
#pragma unroll
    for (int mt = 0; mt < 4; ++mt) {
      int m = mt * 16 + l, c = ks * 4 + q;
      A[mt] = *(const bf16x8*)(xs + m * 128 + (((c ^ l) & 15) << 3));
    }
#pragma unroll
    for (int mt = 0; mt < 4; ++mt) {
      Cr[mt] = mfma16(A[mt], Br[ks], Cr[mt]);
      Cz[mt] = mfma16(A[mt], Bz[ks], Cz[mt]);
      Cn[mt] = mfma16(A[mt], Bn[ks], Cn[mt]);
    }
  }

  const float bR = b_ih[j] + b_hh[j];
  const float bZ = b_ih[128 + j] + b_hh[128 + j];
  const float bN = b_ih[256 + j];
  const float bH = b_hh[256 + j];

#pragma unroll
  for (int mt = 0; mt < 4; ++mt) {
#pragma unroll
    for (int e = 0; e < 4; ++e) {
      const int b = mt * 16 + q * 4 + e;
      float r  = sigm(Cr[mt][e] + bR);
      float zc = sigmc(Cz[mt][e] + bZ);          // zc = 1 - z
      float nv = tanhf_(Cn[mt][e] + bN + r * bH);
      float hv = zc * nv;                        // hp = 0
      hout[(size_t)(node * 64 + b) * 128 + j] = f2b(hv);
    }
  }
}

// ---------------------------------------------------------------------------
// Fused attention + GRU for one inner level. grid = n parents, block 512.
// Per child a: stage 16KB slab -> MFMA u -> tanh/ctx row-dot -> s partials.
// Softmax over a; h0 = sum_a alpha*child (global re-read, L2-warm) into LDS;
// then GRU (K=256 concat via xs/hs arrays). h0 never touches global.
// ---------------------------------------------------------------------------
__global__ __launch_bounds__(512, 2) void fused_attn_gru(
    const unsigned short* __restrict__ hch,   // children base (level d+1 rows)
    const int*            __restrict__ tok,
    const unsigned short* __restrict__ embb,
    const unsigned short* __restrict__ wih,
    const unsigned short* __restrict__ whh,
    const unsigned short* __restrict__ swt,
    const float*          __restrict__ sb,
    const float*          __restrict__ ctx,
    const float*          __restrict__ b_ih,
    const float*          __restrict__ b_hh,
    unsigned short*       __restrict__ hout)
{
  __shared__ unsigned short chs[8192];   // 16 KB: current child slab
  __shared__ unsigned short xs[8192];    // 16 KB: parent x
  __shared__ unsigned short hs[8192];    // 16 KB: h0 (gru-ready swizzle)
  __shared__ float spart[8][256];        // 8 KB
  __shared__ float alf[256];             // 1 KB

  const int p = blockIdx.x;
  const int t = threadIdx.x;
  const int w = __builtin_amdgcn_readfirstlane(t >> 6);
  const int lane = t & 63, l = lane & 15, q = lane >> 4;

  // phase 0: stage parent x (independent of attention)
  {
    const int* tp = tok + p * 64;
#pragma unroll
    for (int i = 0; i < 2; ++i) {
      int g = t + 512 * i;
      int m = g >> 4, c = g & 15;
      uint4 v = *(const uint4*)(embb + (size_t)tp[m] * 128 + c * 8);
      *(uint4*)(xs + m * 128 + ((c ^ (m & 15)) << 3)) = v;
    }
  }

  // attention B frags: wave w owns u-cols k = w*16 + l
  bf16x8 Bs[4];
#pragma unroll
  for (int ks = 0; ks < 4; ++ks)
    Bs[ks] = *(const bf16x8*)(swt + (size_t)(w * 16 + l) * 128 + ks * 32 + q * 8);
  const float sbk = sb[w * 16 + l], cxk = ctx[w * 16 + l];

  // phase A: per-child u MFMA + s partials
  for (int a = 0; a < 4; ++a) {
    __syncthreads();                     // prev iter's MFMA reads done
    const unsigned short* src = hch + (size_t)(4 * p + a) * 8192;
#pragma unroll
    for (int i = 0; i < 2; ++i) {
      int g = t + 512 * i;
      int m = g >> 4, c = g & 15;
      uint4 v = *(const uint4*)(src + m * 128 + c * 8);
      *(uint4*)(chs + m * 128 + ((c ^ (m & 15)) << 3)) = v;
    }
    __syncthreads();

    f32x4 Cu[4] = {};
#pragma unroll
    for (int ks = 0; ks < 4; ++ks) {
#pragma unroll
      for (int mt = 0; mt < 4; ++mt) {
        int m = mt * 16 + l, c = ks * 4 + q;
        bf16x8 A = *(const bf16x8*)(chs + m * 128 + (((c ^ l) & 15) << 3));
        Cu[mt] = mfma16(A, Bs[ks], Cu[mt]);
      }
    }
#pragma unroll
    for (int mt = 0; mt < 4; ++mt) {
      float pe[4];
#pragma unroll
      for (int e = 0; e < 4; ++e) pe[e] = tanhf_(Cu[mt][e] + sbk) * cxk;
#pragma unroll
      for (int mask = 1; mask < 16; mask <<= 1)
#pragma unroll
        for (int e = 0; e < 4; ++e) pe[e] += __shfl_xor(pe[e], mask, 16);
      if (l == 0) {
#pragma unroll
        for (int e = 0; e < 4; ++e)
          spart[w][a * 64 + mt * 16 + q * 4 + e] = pe[e];
      }
    }
  }
  __syncthreads();

  // phase B: s = tanh(sum over waves); softmax over a
  if (t < 256) {
    float s = spart[0][t] + spart[1][t] + spart[2][t] + spart[3][t]
            + spart[4][t] + spart[5][t] + spart[6][t] + spart[7][t];
    spart[0][t] = tanhf_(s);
  }
  __syncthreads();
  if (t < 64) {
    float s0 = spart[0][t], s1 = spart[0][64 + t], s2 = spart[0][128 + t], s3 = spart[0][192 + t];
    float m = fmaxf(fmaxf(s0, s1), fmaxf(s2, s3));
    float e0 = __expf(s0 - m), e1 = __expf(s1 - m), e2 = __expf(s2 - m), e3 = __expf(s3 - m);
    float inv = 1.0f / (e0 + e1 + e2 + e3);
    alf[t] = e0 * inv; alf[64 + t] = e1 * inv; alf[128 + t] = e2 * inv; alf[192 + t] = e3 * inv;
  }
  __syncthreads();

  // phase C: h0 = sum_a alpha * child (children re-read from global, L2-warm)
#pragma unroll
  for (int i = 0; i < 2; ++i) {
    int id = t + 512 * i;                // (b, chunk)
    int b = id >> 4, c = id & 15;
    const unsigned short* c0 = hch + (size_t)(4 * p) * 8192 + b * 128 + c * 8;
    float a0 = alf[b], a1 = alf[64 + b], a2 = alf[128 + b], a3 = alf[192 + b];
    uint4 v0 = *(const uint4*)(c0);
    uint4 v1 = *(const uint4*)(c0 + 8192);
    uint4 v2 = *(const uint4*)(c0 + 16384);
    uint4 v3 = *(const uint4*)(c0 + 24576);
    const unsigned short* e0 = (const unsigned short*)&v0;
    const unsigned short* e1 = (const unsigned short*)&v1;
    const unsigned short* e2 = (const unsigned short*)&v2;
    const unsigned short* e3 = (const unsigned short*)&v3;
    union { unsigned short u[8]; uint4 v; } o;
#pragma unroll
    for (int k = 0; k < 8; ++k)
      o.u[k] = f2b(a0 * b2f(e0[k]) + a1 * b2f(e1[k]) + a2 * b2f(e2[k]) + a3 * b2f(e3[k]));
    *(uint4*)(hs + b * 128 + ((c ^ (b & 15)) << 3)) = o.v;
  }
  __syncthreads();

  // phase D: GRU for parent p (xs: ks 0..3, hs: ks 4..7)
  const int j = w * 16 + l;
  bf16x8 Br[8], Bz[8], Bn[4], Bh[4];
#pragma unroll
  for (int ks = 0; ks < 4; ++ks) {
    const int ko = ks * 32 + q * 8;
    Br[ks] = *(const bf16x8*)(wih + (size_t)j * 128 + ko);
    Bz[ks] = *(const bf16x8*)(wih + (size_t)(128 + j) * 128 + ko);
    Bn[ks] = *(const bf16x8*)(wih + (size_t)(256 + j) * 128 + ko);
    Br[4 + ks] = *(const bf16x8*)(whh + (size_t)j * 128 + ko);
    Bz[4 + ks] = *(const bf16x8*)(whh + (size_t)(128 + j) * 128 + ko);
    Bh[ks]     = *(const bf16x8*)(whh + (size_t)(256 + j) * 128 + ko);
  }

  f32x4 Cr[4] = {}, Cz[4] = {}, Cn[4] = {}, Ch[4] = {};
#pragma unroll
  for (int ks = 0; ks < 8; ++ks) {
    const unsigned short* base = (ks < 4) ? xs : hs;
    const int kk = ks & 3;
    bf16x8 A[4];
#pragma unroll
    for (int mt = 0; mt < 4; ++mt) {
      int m = mt * 16 + l, c = kk * 4 + q;
      A[mt] = *(const bf16x8*)(base + m * 128 + (((c ^ l) & 15) << 3));
    }
#pragma unroll
    for (int mt = 0; mt < 4; ++mt) {
      Cr[mt] = mfma16(A[mt], Br[ks], Cr[mt]);
      Cz[mt] = mfma16(A[mt], Bz[ks], Cz[mt]);
      if (ks < 4) Cn[mt] = mfma16(A[mt], Bn[kk], Cn[mt]);
      else        Ch[mt] = mfma16(A[mt], Bh[kk], Ch[mt]);
    }
  }

  const float bR = b_ih[j] + b_hh[j];
  const float bZ = b_ih[128 + j] + b_hh[128 + j];
  const float bN = b_ih[256 + j];
  const float bH = b_hh[256 + j];
  const int c16 = j >> 3;

#pragma unroll
  for (int mt = 0; mt < 4; ++mt) {
#pragma unroll
    for (int e = 0; e < 4; ++e) {
      const int b = mt * 16 + q * 4 + e;
      float r  = sigm(Cr[mt][e] + bR);
      float zc = sigmc(Cz[mt][e] + bZ);          // zc = 1 - z
      float nv = tanhf_(Cn[mt][e] + bN + r * (Ch[mt][e] + bH));
      float hp = b2f(hs[b * 128 + (((c16 ^ (b & 15)) & 15) << 3) + (j & 7)]);
      float hv = fmaf(zc, nv - hp, hp);          // hp + (1-z)(nv - hp)
      hout[(size_t)(p * 64 + b) * 128 + j] = f2b(hv);
    }
  }
}

extern "C" void kernel_launch(void* const* d_in, const int* in_sizes, int n_in,
                              void* d_out, int out_size, void* d_ws, size_t ws_size,
                              hipStream_t stream) {
  const int*   tokens = (const int*)d_in[0];
  const float* emb    = (const float*)d_in[1];
  const float* sent_w = (const float*)d_in[2];
  const float* sent_b = (const float*)d_in[3];
  const float* ctx_w  = (const float*)d_in[4];
  const float* w_ih   = (const float*)d_in[5];
  const float* w_hh   = (const float*)d_in[6];
  const float* b_ih   = (const float*)d_in[7];
  const float* b_hh   = (const float*)d_in[8];

  char* ws = (char*)d_ws;
  unsigned*       acc  = (unsigned*)(ws + WS_ACC);
  unsigned short* wihb = (unsigned short*)(ws + WS_WIH);
  unsigned short* whhb = (unsigned short*)(ws + WS_WHH);
  unsigned short* swtb = (unsigned short*)(ws + WS_SWT);
  unsigned short* embb = (unsigned short*)(ws + WS_EMB);
  unsigned short* H    = (unsigned short*)(ws + WS_H);

  hipLaunchKernelGGL(prep_emb, dim3(6250), dim3(256), 0, stream, emb, embb);
  hipLaunchKernelGGL(prep_w, dim3(448), dim3(256), 0, stream,
                     w_ih, w_hh, sent_w, wihb, whhb, swtb);

  static const int offs[7] = {0, 1, 5, 21, 85, 341, 1365};

  // leaves (d=6)
  hipLaunchKernelGGL(gru_leaf, dim3(4096), dim3(512), 0, stream,
                     tokens + (size_t)offs[6] * 64, embb, wihb, b_ih, b_hh,
                     H + (size_t)offs[6] * 8192);

  // inner levels d=5..0
  for (int d = 5; d >= 0; --d) {
    int n = 1 << (2 * d);
    hipLaunchKernelGGL(fused_attn_gru, dim3(n), dim3(512), 0, stream,
                       H + (size_t)offs[d + 1] * 8192,
                       tokens + (size_t)offs[d] * 64,
                       embb, wihb, whhb, swtb, sent_b, ctx_w, b_ih, b_hh,
                       H + (size_t)offs[d] * 8192);
  }

  hipLaunchKernelGGL(reduce_all, dim3(8, 64), dim3(256), 0, stream, H, acc);
  hipLaunchKernelGGL(decode_out, dim3(32), dim3(256), 0, stream, acc, (float*)d_out);
}

// Round 6
// 384.781 us; speedup vs baseline: 1.6259x; 1.0434x over previous
//
#include <hip/hip_runtime.h>
#include <cstdint>
#include <cstddef>

// ---------------------------------------------------------------------------
// BatchTreeEncoder on MFMA: A=4, D=7, B=64, E=128, H=128, N_NODES=5461
// R6: subtree-max recursion P[p] = max(h_p, max_a P[child_a]) computed inside
// the fused kernels (P[leaf] = h_leaf aliases H). Root P is the output ->
// reduce_all deleted. Epilogues store via LDS transpose (dwordx4, not 16x
// store_short). 9 dispatches.
// ---------------------------------------------------------------------------

typedef short  bf16x8 __attribute__((ext_vector_type(8)));
typedef float  f32x4  __attribute__((ext_vector_type(4)));

// workspace layout (bytes)
#define WS_WIH   0u                        // 384*128*2
#define WS_WHH   (WS_WIH + 98304u)
#define WS_SWT   (WS_WHH + 98304u)         // 128*128*2
#define WS_EMB   (WS_SWT + 32768u)         // 50000*128*2 = 12.8 MB
#define WS_P     (WS_EMB + 12800000u)      // 1365*8192*2 = 22.4 MB (inner P)
#define WS_H     (WS_P + 22364160u)        // 5461*8192*2 = 89.5 MB
// total ~124.6 MB

__device__ __forceinline__ float sigm(float x)   { return 1.0f / (1.0f + __expf(-x)); }
__device__ __forceinline__ float sigmc(float x)  { return 1.0f / (1.0f + __expf(x)); }   // 1-sigm
__device__ __forceinline__ float tanhf_(float x) { return 1.0f - 2.0f / (1.0f + __expf(2.0f * x)); }

__device__ __forceinline__ unsigned short f2b(float f) {
  unsigned u = __float_as_uint(f);
  u += 0x7fffu + ((u >> 16) & 1u);     // RNE (no NaN here)
  return (unsigned short)(u >> 16);
}
__device__ __forceinline__ float b2f(unsigned short s) {
  return __uint_as_float(((unsigned)s) << 16);
}

__device__ __forceinline__ f32x4 mfma16(bf16x8 a, bf16x8 b, f32x4 c) {
  return __builtin_amdgcn_mfma_f32_16x16x32_bf16(a, b, c, 0, 0, 0);
}

// P[root] is the final (64,128) max in bf16
__global__ __launch_bounds__(256) void decode_out(const unsigned short* __restrict__ P0,
                                                  float* __restrict__ out) {
  int i = blockIdx.x * 256 + threadIdx.x;              // grid 32
  out[i] = b2f(P0[i]);
}

// merged prep: emb fp32->bf16 (first 6250 blocks), weights + swT (last 448)
__global__ __launch_bounds__(256) void prep_all(const float* __restrict__ emb,
                                                const float* __restrict__ wih,
                                                const float* __restrict__ whh,
                                                const float* __restrict__ sw,
                                                unsigned short* __restrict__ embb,
                                                unsigned short* __restrict__ wihb,
                                                unsigned short* __restrict__ whhb,
                                                unsigned short* __restrict__ swtb) {
  int i = blockIdx.x * 256 + threadIdx.x;              // grid 6698
  if (i < 1600000) {                                   // 1.6M float4s of emb
    float4 v = *(const float4*)(emb + (size_t)i * 4);
    ushort4 o; o.x = f2b(v.x); o.y = f2b(v.y); o.z = f2b(v.z); o.w = f2b(v.w);
    *(ushort4*)(embb + (size_t)i * 4) = o;
  } else {
    int j = i - 1600000;                               // 0..114687
    if (j < 49152)       wihb[j] = f2b(wih[j]);
    else if (j < 98304)  whhb[j - 49152] = f2b(whh[j - 49152]);
    else { int k = j - 98304; int ku = k >> 7; int h = k & 127; swtb[k] = f2b(sw[h * 128 + ku]); }
  }
}

// ---------------------------------------------------------------------------
// Leaf GRU (h0 = 0): grid 4096, block 512 (8 waves). Wave w owns j = w*16+l.
// Epilogue through LDS (stride 136: <=2-way bank alias = free) -> dwordx4.
// ---------------------------------------------------------------------------
__global__ __launch_bounds__(512, 2) void gru_leaf(
    const int*            __restrict__ tok,
    const unsigned short* __restrict__ embb,
    const unsigned short* __restrict__ wih,
    const float*          __restrict__ b_ih,
    const float*          __restrict__ b_hh,
    unsigned short*       __restrict__ hout)
{
  __shared__ unsigned short xs[8192];
  __shared__ unsigned short hvb[64 * 136];

  const int node = blockIdx.x;
  const int t = threadIdx.x;

  {
    const int* tp = tok + node * 64;
#pragma unroll
    for (int i = 0; i < 2; ++i) {
      int g = t + 512 * i;
      int m = g >> 4, c = g & 15;
      uint4 v = *(const uint4*)(embb + (size_t)tp[m] * 128 + c * 8);
      *(uint4*)(xs + m * 128 + ((c ^ (m & 15)) << 3)) = v;
    }
  }

  const int w = __builtin_amdgcn_readfirstlane(t >> 6);
  const int lane = t & 63, l = lane & 15, q = lane >> 4;
  const int j = w * 16 + l;

  bf16x8 Br[4], Bz[4], Bn[4];
#pragma unroll
  for (int ks = 0; ks < 4; ++ks) {
    const int ko = ks * 32 + q * 8;
    Br[ks] = *(const bf16x8*)(wih + (size_t)j * 128 + ko);
    Bz[ks] = *(const bf16x8*)(wih + (size_t)(128 + j) * 128 + ko);
    Bn[ks] = *(const bf16x8*)(wih + (size_t)(256 + j) * 128 + ko);
  }

  f32x4 Cr[4] = {}, Cz[4] = {}, Cn[4] = {};
  __syncthreads();

#pragma unroll
  for (int ks = 0; ks < 4; ++ks) {
    bf16x8 A[4];
#pragma unroll
    for (int mt = 0; mt < 4; ++mt) {
      int m = mt * 16 + l, c = ks * 4 + q;
      A[mt] = *(const bf16x8*)(xs + m * 128 + (((c ^ l) & 15) << 3));
    }
#pragma unroll
    for (int mt = 0; mt < 4; ++mt) {
      Cr[mt] = mfma16(A[mt], Br[ks], Cr[mt]);
      Cz[mt] = mfma16(A[mt], Bz[ks], Cz[mt]);
      Cn[mt] = mfma16(A[mt], Bn[ks], Cn[mt]);
    }
  }

  const float bR = b_ih[j] + b_hh[j];
  const float bZ = b_ih[128 + j] + b_hh[128 + j];
  const float bN = b_ih[256 + j];
  const float bH = b_hh[256 + j];

#pragma unroll
  for (int mt = 0; mt < 4; ++mt) {
#pragma unroll
    for (int e = 0; e < 4; ++e) {
      const int b = mt * 16 + q * 4 + e;
      float r  = sigm(Cr[mt][e] + bR);
      float zc = sigmc(Cz[mt][e] + bZ);
      float nv = tanhf_(Cn[mt][e] + bN + r * bH);
      hvb[b * 136 + j] = f2b(zc * nv);           // hp = 0
    }
  }
  __syncthreads();

#pragma unroll
  for (int i = 0; i < 2; ++i) {
    int g = t + 512 * i;
    int m = g >> 4, c = g & 15;
    uint4 v = *(const uint4*)(hvb + m * 136 + c * 8);
    *(uint4*)(hout + (size_t)(node * 64 + m) * 128 + c * 8) = v;
  }
}

// ---------------------------------------------------------------------------
// Fused attention + GRU + subtree-max for one inner level. grid = n parents.
// LEAF_CHILD: children are leaves -> child P = staged child h (fold free).
// Else: fold 4 child-P slabs (small levels). Emits hout AND Pout (dwordx4).
// ---------------------------------------------------------------------------
template <bool LEAF_CHILD>
__global__ __launch_bounds__(512, 2) void fused_attn_gru(
    const unsigned short* __restrict__ hch,   // children h base
    const unsigned short* __restrict__ Pch,   // children P base (unused if LEAF_CHILD)
    const int*            __restrict__ tok,
    const unsigned short* __restrict__ embb,
    const unsigned short* __restrict__ wih,
    const unsigned short* __restrict__ whh,
    const unsigned short* __restrict__ swt,
    const float*          __restrict__ sb,
    const float*          __restrict__ ctx,
    const float*          __restrict__ b_ih,
    const float*          __restrict__ b_hh,
    unsigned short*       __restrict__ hout,
    unsigned short*       __restrict__ Pout)
{
  __shared__ unsigned short chv[64 * 136];  // child slab (<=8192) / hv transpose
  __shared__ unsigned short xs[8192];       // parent x
  __shared__ unsigned short hs[8192];       // h0 (gru-ready swizzle)
  __shared__ float spart[8][256];
  __shared__ float alf[256];

  const int p = blockIdx.x;
  const int t = threadIdx.x;
  const int w = __builtin_amdgcn_readfirstlane(t >> 6);
  const int lane = t & 63, l = lane & 15, q = lane >> 4;

  // running subtree max per (b,c) staging slot
  float rm[2][8];
#pragma unroll
  for (int k = 0; k < 8; ++k) { rm[0][k] = -3.0e38f; rm[1][k] = -3.0e38f; }

  // phase 0: stage parent x
  {
    const int* tp = tok + p * 64;
#pragma unroll
    for (int i = 0; i < 2; ++i) {
      int g = t + 512 * i;
      int m = g >> 4, c = g & 15;
      uint4 v = *(const uint4*)(embb + (size_t)tp[m] * 128 + c * 8);
      *(uint4*)(xs + m * 128 + ((c ^ (m & 15)) << 3)) = v;
    }
  }

  bf16x8 Bs[4];
#pragma unroll
  for (int ks = 0; ks < 4; ++ks)
    Bs[ks] = *(const bf16x8*)(swt + (size_t)(w * 16 + l) * 128 + ks * 32 + q * 8);
  const float sbk = sb[w * 16 + l], cxk = ctx[w * 16 + l];

  // phase A: per-child u MFMA + s partials (+ leaf-child P fold during staging)
  for (int a = 0; a < 4; ++a) {
    __syncthreads();
    const unsigned short* src = hch + (size_t)(4 * p + a) * 8192;
#pragma unroll
    for (int i = 0; i < 2; ++i) {
      int g = t + 512 * i;
      int m = g >> 4, c = g & 15;
      uint4 v = *(const uint4*)(src + m * 128 + c * 8);
      *(uint4*)(chv + m * 128 + ((c ^ (m & 15)) << 3)) = v;
      if constexpr (LEAF_CHILD) {
        const unsigned short* e = (const unsigned short*)&v;
#pragma unroll
        for (int k = 0; k < 8; ++k) rm[i][k] = fmaxf(rm[i][k], b2f(e[k]));
      }
    }
    __syncthreads();

    f32x4 Cu[4] = {};
#pragma unroll
    for (int ks = 0; ks < 4; ++ks) {
#pragma unroll
      for (int mt = 0; mt < 4; ++mt) {
        int m = mt * 16 + l, c = ks * 4 + q;
        bf16x8 A = *(const bf16x8*)(chv + m * 128 + (((c ^ l) & 15) << 3));
        Cu[mt] = mfma16(A, Bs[ks], Cu[mt]);
      }
    }
#pragma unroll
    for (int mt = 0; mt < 4; ++mt) {
      float pe[4];
#pragma unroll
      for (int e = 0; e < 4; ++e) pe[e] = tanhf_(Cu[mt][e] + sbk) * cxk;
#pragma unroll
      for (int mask = 1; mask < 16; mask <<= 1)
#pragma unroll
        for (int e = 0; e < 4; ++e) pe[e] += __shfl_xor(pe[e], mask, 16);
      if (l == 0) {
#pragma unroll
        for (int e = 0; e < 4; ++e)
          spart[w][a * 64 + mt * 16 + q * 4 + e] = pe[e];
      }
    }
  }
  __syncthreads();

  // phase B: s = tanh(sum over waves); softmax over a
  if (t < 256) {
    float s = spart[0][t] + spart[1][t] + spart[2][t] + spart[3][t]
            + spart[4][t] + spart[5][t] + spart[6][t] + spart[7][t];
    spart[0][t] = tanhf_(s);
  }
  __syncthreads();
  if (t < 64) {
    float s0 = spart[0][t], s1 = spart[0][64 + t], s2 = spart[0][128 + t], s3 = spart[0][192 + t];
    float m = fmaxf(fmaxf(s0, s1), fmaxf(s2, s3));
    float e0 = __expf(s0 - m), e1 = __expf(s1 - m), e2 = __expf(s2 - m), e3 = __expf(s3 - m);
    float inv = 1.0f / (e0 + e1 + e2 + e3);
    alf[t] = e0 * inv; alf[64 + t] = e1 * inv; alf[128 + t] = e2 * inv; alf[192 + t] = e3 * inv;
  }
  __syncthreads();

  // phase C: h0 = sum_a alpha * child (global re-read, L2-warm); inner P fold
#pragma unroll
  for (int i = 0; i < 2; ++i) {
    int id = t + 512 * i;
    int b = id >> 4, c = id & 15;
    const unsigned short* c0 = hch + (size_t)(4 * p) * 8192 + b * 128 + c * 8;
    float a0 = alf[b], a1 = alf[64 + b], a2 = alf[128 + b], a3 = alf[192 + b];
    uint4 v0 = *(const uint4*)(c0);
    uint4 v1 = *(const uint4*)(c0 + 8192);
    uint4 v2 = *(const uint4*)(c0 + 16384);
    uint4 v3 = *(const uint4*)(c0 + 24576);
    const unsigned short* e0 = (const unsigned short*)&v0;
    const unsigned short* e1 = (const unsigned short*)&v1;
    const unsigned short* e2 = (const unsigned short*)&v2;
    const unsigned short* e3 = (const unsigned short*)&v3;
    union { unsigned short u[8]; uint4 v; } o;
#pragma unroll
    for (int k = 0; k < 8; ++k)
      o.u[k] = f2b(a0 * b2f(e0[k]) + a1 * b2f(e1[k]) + a2 * b2f(e2[k]) + a3 * b2f(e3[k]));
    *(uint4*)(hs + b * 128 + ((c ^ (b & 15)) << 3)) = o.v;

    if constexpr (!LEAF_CHILD) {
      const unsigned short* pc = Pch + (size_t)(4 * p) * 8192 + b * 128 + c * 8;
      uint4 p0 = *(const uint4*)(pc);
      uint4 p1 = *(const uint4*)(pc + 8192);
      uint4 p2 = *(const uint4*)(pc + 16384);
      uint4 p3 = *(const uint4*)(pc + 24576);
      const unsigned short* f0 = (const unsigned short*)&p0;
      const unsigned short* f1 = (const unsigned short*)&p1;
      const unsigned short* f2 = (const unsigned short*)&p2;
      const unsigned short* f3 = (const unsigned short*)&p3;
#pragma unroll
      for (int k = 0; k < 8; ++k)
        rm[i][k] = fmaxf(rm[i][k],
                   fmaxf(fmaxf(b2f(f0[k]), b2f(f1[k])), fmaxf(b2f(f2[k]), b2f(f3[k]))));
    }
  }
  __syncthreads();

  // phase D: GRU (xs: ks 0..3, hs: ks 4..7)
  const int j = w * 16 + l;
  bf16x8 Br[8], Bz[8], Bn[4], Bh[4];
#pragma unroll
  for (int ks = 0; ks < 4; ++ks) {
    const int ko = ks * 32 + q * 8;
    Br[ks] = *(const bf16x8*)(wih + (size_t)j * 128 + ko);
    Bz[ks] = *(const bf16x8*)(wih + (size_t)(128 + j) * 128 + ko);
    Bn[ks] = *(const bf16x8*)(wih + (size_t)(256 + j) * 128 + ko);
    Br[4 + ks] = *(const bf16x8*)(whh + (size_t)j * 128 + ko);
    Bz[4 + ks] = *(const bf16x8*)(whh + (size_t)(128 + j) * 128 + ko);
    Bh[ks]     = *(const bf16x8*)(whh + (size_t)(256 + j) * 128 + ko);
  }

  f32x4 Cr[4] = {}, Cz[4] = {}, Cn[4] = {}, Ch[4] = {};
#pragma unroll
  for (int ks = 0; ks < 8; ++ks) {
    const unsigned short* base = (ks < 4) ? xs : hs;
    const int kk = ks & 3;
    bf16x8 A[4];
#pragma unroll
    for (int mt = 0; mt < 4; ++mt) {
      int m = mt * 16 + l, c = kk * 4 + q;
      A[mt] = *(const bf16x8*)(base + m * 128 + (((c ^ l) & 15) << 3));
    }
#pragma unroll
    for (int mt = 0; mt < 4; ++mt) {
      Cr[mt] = mfma16(A[mt], Br[ks], Cr[mt]);
      Cz[mt] = mfma16(A[mt], Bz[ks], Cz[mt]);
      if (ks < 4) Cn[mt] = mfma16(A[mt], Bn[kk], Cn[mt]);
      else        Ch[mt] = mfma16(A[mt], Bh[kk], Ch[mt]);
    }
  }

  const float bR = b_ih[j] + b_hh[j];
  const float bZ = b_ih[128 + j] + b_hh[128 + j];
  const float bN = b_ih[256 + j];
  const float bH = b_hh[256 + j];
  const int c16 = j >> 3;

#pragma unroll
  for (int mt = 0; mt < 4; ++mt) {
#pragma unroll
    for (int e = 0; e < 4; ++e) {
      const int b = mt * 16 + q * 4 + e;
      float r  = sigm(Cr[mt][e] + bR);
      float zc = sigmc(Cz[mt][e] + bZ);
      float nv = tanhf_(Cn[mt][e] + bN + r * (Ch[mt][e] + bH));
      float hp = b2f(hs[b * 128 + (((c16 ^ (b & 15)) & 15) << 3) + (j & 7)]);
      chv[b * 136 + j] = f2b(fmaf(zc, nv - hp, hp));
    }
  }
  __syncthreads();

  // final: hout + Pout = max(hv, child subtree max), both dwordx4
#pragma unroll
  for (int i = 0; i < 2; ++i) {
    int g = t + 512 * i;
    int m = g >> 4, c = g & 15;
    uint4 v = *(const uint4*)(chv + m * 136 + c * 8);
    *(uint4*)(hout + (size_t)(p * 64 + m) * 128 + c * 8) = v;
    const unsigned short* e = (const unsigned short*)&v;
    union { unsigned short u[8]; uint4 v4; } pv;
#pragma unroll
    for (int k = 0; k < 8; ++k)
      pv.u[k] = f2b(fmaxf(rm[i][k], b2f(e[k])));   // exact: max of bf16 values
    *(uint4*)(Pout + (size_t)(p * 64 + m) * 128 + c * 8) = pv.v4;
  }
}

extern "C" void kernel_launch(void* const* d_in, const int* in_sizes, int n_in,
                              void* d_out, int out_size, void* d_ws, size_t ws_size,
                              hipStream_t stream) {
  const int*   tokens = (const int*)d_in[0];
  const float* emb    = (const float*)d_in[1];
  const float* sent_w = (const float*)d_in[2];
  const float* sent_b = (const float*)d_in[3];
  const float* ctx_w  = (const float*)d_in[4];
  const float* w_ih   = (const float*)d_in[5];
  const float* w_hh   = (const float*)d_in[6];
  const float* b_ih   = (const float*)d_in[7];
  const float* b_hh   = (const float*)d_in[8];

  char* ws = (char*)d_ws;
  unsigned short* wihb = (unsigned short*)(ws + WS_WIH);
  unsigned short* whhb = (unsigned short*)(ws + WS_WHH);
  unsigned short* swtb = (unsigned short*)(ws + WS_SWT);
  unsigned short* embb = (unsigned short*)(ws + WS_EMB);
  unsigned short* P    = (unsigned short*)(ws + WS_P);
  unsigned short* H    = (unsigned short*)(ws + WS_H);

  hipLaunchKernelGGL(prep_all, dim3(6698), dim3(256), 0, stream,
                     emb, w_ih, w_hh, sent_w, embb, wihb, whhb, swtb);

  static const int offs[7] = {0, 1, 5, 21, 85, 341, 1365};

  // leaves (d=6): P aliases H
  hipLaunchKernelGGL(gru_leaf, dim3(4096), dim3(512), 0, stream,
                     tokens + (size_t)offs[6] * 64, embb, wihb, b_ih, b_hh,
                     H + (size_t)offs[6] * 8192);

  // d=5: children are leaves (child P = child h, folded during staging)
  hipLaunchKernelGGL((fused_attn_gru<true>), dim3(1024), dim3(512), 0, stream,
                     H + (size_t)offs[6] * 8192, (const unsigned short*)nullptr,
                     tokens + (size_t)offs[5] * 64,
                     embb, wihb, whhb, swtb, sent_b, ctx_w, b_ih, b_hh,
                     H + (size_t)offs[5] * 8192, P + (size_t)offs[5] * 8192);

  // d=4..0: children are inner (explicit child-P fold)
  for (int d = 4; d >= 0; --d) {
    int n = 1 << (2 * d);
    hipLaunchKernelGGL((fused_attn_gru<false>), dim3(n), dim3(512), 0, stream,
                       H + (size_t)offs[d + 1] * 8192, P + (size_t)offs[d + 1] * 8192,
                       tokens + (size_t)offs[d] * 64,
                       embb, wihb, whhb, swtb, sent_b, ctx_w, b_ih, b_hh,
                       H + (size_t)offs[d] * 8192, P + (size_t)offs[d] * 8192);
  }

  hipLaunchKernelGGL(decode_out, dim3(32), dim3(256), 0, stream, P, (float*)d_out);
}